// Round 10
// baseline (1471.268 us; speedup 1.0000x reference)
//
#include <hip/hip_runtime.h>
#include <hip/hip_bf16.h>

#define B_   8
#define T_   2048
#define C_   1024
#define FFN_ 4096
#define M_   (B_ * T_)   // 16384
#define EPS_ 1e-5f

typedef __bf16 bf16x8 __attribute__((ext_vector_type(8)));
typedef float  f32x4  __attribute__((ext_vector_type(4)));

__device__ __forceinline__ unsigned short f2bf(float f) {
    union { float f; unsigned int u; } c; c.f = f;
    unsigned int u = c.u;
    u += 0x7fffu + ((u >> 16) & 1u);   // round-to-nearest-even
    return (unsigned short)(u >> 16);
}
__device__ __forceinline__ float bf2f(unsigned short h) {
    union { unsigned int u; float f; } c; c.u = ((unsigned int)h) << 16;
    return c.f;
}

// ---------------- weight fp32 [R][Cc] -> bf16 transposed [Cc][R] ----------------
__global__ __launch_bounds__(256) void wconv_t(const float* __restrict__ src,
                                               unsigned short* __restrict__ dst,
                                               int R, int Cc) {
    __shared__ float tile[32][33];
    int tx = threadIdx.x, ty = threadIdx.y;       // block (32,8)
    int c0 = blockIdx.x * 32;
    int r0 = blockIdx.y * 32;
#pragma unroll
    for (int i = 0; i < 4; ++i)
        tile[ty + i * 8][tx] = src[(size_t)(r0 + ty + i * 8) * Cc + c0 + tx];
    __syncthreads();
#pragma unroll
    for (int i = 0; i < 4; ++i)
        dst[(size_t)(c0 + ty + i * 8) * R + r0 + tx] = f2bf(tile[tx][ty + i * 8]);
}

// ---------------- block LN stats (256 threads, C=1024, float4/thread) ----------------
__device__ __forceinline__ void block_stats(const float4* __restrict__ p4, int tid,
                                            float* red, float& mean, float& rstd) {
    float4 v = p4[tid];
    float s = v.x + v.y + v.z + v.w;
    float q = v.x * v.x + v.y * v.y + v.z * v.z + v.w * v.w;
#pragma unroll
    for (int off = 32; off >= 1; off >>= 1) {
        s += __shfl_down(s, off, 64);
        q += __shfl_down(q, off, 64);
    }
    int lane = tid & 63, wv = tid >> 6;
    if (lane == 0) { red[wv] = s; red[4 + wv] = q; }
    __syncthreads();
    s = red[0] + red[1] + red[2] + red[3];
    q = red[4] + red[5] + red[6] + red[7];
    mean = s * (1.0f / C_);
    float var = q * (1.0f / C_) - mean * mean;
    rstd = rsqrtf(var + EPS_);
    __syncthreads();   // before red reuse
}

// ---------------- LN1 + token-shift + 3-way mix -> bf16 kx,vx,rx ----------------
__global__ __launch_bounds__(256) void mix1_kernel(
    const float* __restrict__ x, const float* __restrict__ lnw, const float* __restrict__ lnb,
    const float* __restrict__ tmk, const float* __restrict__ tmv, const float* __restrict__ tmr,
    unsigned short* __restrict__ kx, unsigned short* __restrict__ vx, unsigned short* __restrict__ rx) {
    __shared__ float red[8];
    int token = blockIdx.x;
    int t = token & (T_ - 1);
    int tid = threadIdx.x;
    bool hp = (t != 0);
    const float4* xt = (const float4*)(x + (size_t)token * C_);
    const float4* xp = (const float4*)(x + (size_t)(hp ? token - 1 : token) * C_);
    float m1, r1, m0 = 0.f, r0 = 0.f;
    block_stats(xt, tid, red, m1, r1);
    if (hp) block_stats(xp, tid, red, m0, r0);

    float4 xv = xt[tid];
    float4 pv = xp[tid];
    float4 w4 = ((const float4*)lnw)[tid];
    float4 b4 = ((const float4*)lnb)[tid];
    float4 k4 = ((const float4*)tmk)[tid];
    float4 v4 = ((const float4*)tmv)[tid];
    float4 q4 = ((const float4*)tmr)[tid];

    ushort4 ko, vo, ro;
    auto mixone = [&](float xe, float pe, float we, float be, float ke, float ve, float re,
                      unsigned short& koe, unsigned short& voe, unsigned short& roe) {
        float xn = (xe - m1) * r1 * we + be;
        float xs = hp ? ((pe - m0) * r0 * we + be) : 0.f;
        koe = f2bf(xs + ke * (xn - xs));
        voe = f2bf(xs + ve * (xn - xs));
        roe = f2bf(xs + re * (xn - xs));
    };
    mixone(xv.x, pv.x, w4.x, b4.x, k4.x, v4.x, q4.x, ko.x, vo.x, ro.x);
    mixone(xv.y, pv.y, w4.y, b4.y, k4.y, v4.y, q4.y, ko.y, vo.y, ro.y);
    mixone(xv.z, pv.z, w4.z, b4.z, k4.z, v4.z, q4.z, ko.z, vo.z, ro.z);
    mixone(xv.w, pv.w, w4.w, b4.w, k4.w, v4.w, q4.w, ko.w, vo.w, ro.w);
    size_t o = (size_t)token * (C_ / 4) + tid;
    ((ushort4*)kx)[o] = ko;
    ((ushort4*)vx)[o] = vo;
    ((ushort4*)rx)[o] = ro;
}

// ---------------- LN2 + token-shift + 2-way mix -> bf16 kx2,rx2 ----------------
__global__ __launch_bounds__(256) void mix2_kernel(
    const float* __restrict__ att, const float* __restrict__ lnw, const float* __restrict__ lnb,
    const float* __restrict__ cmk, const float* __restrict__ cmr,
    unsigned short* __restrict__ kx, unsigned short* __restrict__ rx) {
    __shared__ float red[8];
    int token = blockIdx.x;
    int t = token & (T_ - 1);
    int tid = threadIdx.x;
    bool hp = (t != 0);
    const float4* xt = (const float4*)(att + (size_t)token * C_);
    const float4* xp = (const float4*)(att + (size_t)(hp ? token - 1 : token) * C_);
    float m1, r1, m0 = 0.f, r0 = 0.f;
    block_stats(xt, tid, red, m1, r1);
    if (hp) block_stats(xp, tid, red, m0, r0);

    float4 xv = xt[tid];
    float4 pv = xp[tid];
    float4 w4 = ((const float4*)lnw)[tid];
    float4 b4 = ((const float4*)lnb)[tid];
    float4 k4 = ((const float4*)cmk)[tid];
    float4 q4 = ((const float4*)cmr)[tid];

    ushort4 ko, ro;
    auto mixone = [&](float xe, float pe, float we, float be, float ke, float re,
                      unsigned short& koe, unsigned short& roe) {
        float xn = (xe - m1) * r1 * we + be;
        float xs = hp ? ((pe - m0) * r0 * we + be) : 0.f;
        koe = f2bf(xs + ke * (xn - xs));
        roe = f2bf(xs + re * (xn - xs));
    };
    mixone(xv.x, pv.x, w4.x, b4.x, k4.x, q4.x, ko.x, ro.x);
    mixone(xv.y, pv.y, w4.y, b4.y, k4.y, q4.y, ko.y, ro.y);
    mixone(xv.z, pv.z, w4.z, b4.z, k4.z, q4.z, ko.z, ro.z);
    mixone(xv.w, pv.w, w4.w, b4.w, k4.w, q4.w, ko.w, ro.w);
    size_t o = (size_t)token * (C_ / 4) + tid;
    ((ushort4*)kx)[o] = ko;
    ((ushort4*)rx)[o] = ro;
}

// ---------------- WKV scan: one thread per (b,c) channel, 8-deep prefetch ----------------
// k f32 [B,T,C]; v bf16; rv bf16 holds r on input and is overwritten IN PLACE with
// bf16(r*wkv) (each element read once by its owning thread before that thread writes it).
__global__ __launch_bounds__(64) void wkv_scan_kernel(
    const float* __restrict__ k, const unsigned short* __restrict__ v,
    unsigned short* rv,
    const float* __restrict__ tf, const float* __restrict__ td) {
    int idx = blockIdx.x * 64 + threadIdx.x;   // 0..B*C-1
    int b = idx >> 10, c = idx & (C_ - 1);
    float w = -expf(td[c]);       // precise: error in w compounds over 2048 steps
    float u = tf[c];
    size_t base = (size_t)b * T_ * C_ + c;
    float a = 0.f, bb = 0.f, p = -1e30f;

    float kA[8], vA[8], rA[8], kB[8], vB[8], rB[8];
#pragma unroll
    for (int j = 0; j < 8; ++j) {
        size_t o = base + (size_t)j * C_;
        kA[j] = k[o]; vA[j] = bf2f(v[o]); rA[j] = bf2f(rv[o]);
    }

    auto step = [&](float kt, float vt, float rt, int t) {
        float uk = u + kt;
        float qq = fmaxf(p, uk);
        float e1 = __expf(p - qq), e2 = __expf(uk - qq);
        float num = e1 * a + e2 * vt;
        float den = e1 * bb + e2;
        float wkv = (den == 0.f) ? 0.f : num / den;
        rv[base + (size_t)t * C_] = f2bf(rt * wkv);
        float cw = w + p;
        float q2 = fmaxf(cw, kt);
        float f1 = __expf(cw - q2), f2e = __expf(kt - q2);
        a = f1 * a + f2e * vt;
        bb = f1 * bb + f2e;
        p = q2;
    };

    for (int t0 = 0; t0 < T_; t0 += 16) {
        // issue loads for t0+8..t0+15 into B (cover ~8 steps of compute)
#pragma unroll
        for (int j = 0; j < 8; ++j) {
            int t = t0 + 8 + j; if (t > T_ - 1) t = T_ - 1;
            size_t o = base + (size_t)t * C_;
            kB[j] = k[o]; vB[j] = bf2f(v[o]); rB[j] = bf2f(rv[o]);
        }
#pragma unroll
        for (int j = 0; j < 8; ++j) step(kA[j], vA[j], rA[j], t0 + j);
        // issue loads for t0+16..t0+23 into A
#pragma unroll
        for (int j = 0; j < 8; ++j) {
            int t = t0 + 16 + j; if (t > T_ - 1) t = T_ - 1;
            size_t o = base + (size_t)t * C_;
            kA[j] = k[o]; vA[j] = bf2f(v[o]); rA[j] = bf2f(rv[o]);
        }
#pragma unroll
        for (int j = 0; j < 8; ++j) step(kB[j], vB[j], rB[j], t0 + 8 + j);
    }
}

// ---------------- bf16 GEMM: C[M,N] = A[M,K] @ Bt[N,K]^T, m97-style 128^2 tile ----------------
// A row stride = K; Bt row stride = ldb (>= K, for FFN-chunked B).
// EPI: 0 = store f32; 2 = +e0f f32; 3 = relu^2 -> bf16; 5 = sigmoid -> bf16;
//      6 = store bf16; 7 = Cf[o] += bf2f(e0b[o]) * val (in-place f32 accumulate)
template<int EPI>
__global__ __launch_bounds__(256) void gemm_bt(
    const unsigned short* __restrict__ A, const unsigned short* __restrict__ Bt,
    float* Cf, unsigned short* Cb,
    const float* __restrict__ e0f, const unsigned short* __restrict__ e0b,
    int M, int N, int K, int ldb) {
    __shared__ unsigned short Als[128 * 32];
    __shared__ unsigned short Bls[128 * 32];
    int tid = threadIdx.x;
    int lane = tid & 63, wv = tid >> 6;
    int wr = wv >> 1, wc = wv & 1;
    int brow = blockIdx.y * 128, bcol = blockIdx.x * 128;

    f32x4 acc[4][4] = {};

    int ar = tid >> 2, ac = (tid & 3) * 8;  // 16B chunk -> (row, col8) within tile
    const unsigned short* ga0 = A + (size_t)(brow + ar) * K + ac;
    const unsigned short* ga1 = A + (size_t)(brow + 64 + ar) * K + ac;
    const unsigned short* gb0 = Bt + (size_t)(bcol + ar) * ldb + ac;
    const unsigned short* gb1 = Bt + (size_t)(bcol + 64 + ar) * ldb + ac;
    unsigned short* la0 = Als + (size_t)(wv * 64) * 8;         // + lane*16B implicit
    unsigned short* la1 = Als + (size_t)((4 + wv) * 64) * 8;
    unsigned short* lb0 = Bls + (size_t)(wv * 64) * 8;
    unsigned short* lb1 = Bls + (size_t)((4 + wv) * 64) * 8;

    int fa = (lane & 15) * 32 + (lane >> 4) * 8;  // fragment base offset

    for (int kt = 0; kt < K; kt += 32) {
        __builtin_amdgcn_global_load_lds((const __attribute__((address_space(1))) void*)(ga0 + kt),
                                         (__attribute__((address_space(3))) void*)la0, 16, 0, 0);
        __builtin_amdgcn_global_load_lds((const __attribute__((address_space(1))) void*)(ga1 + kt),
                                         (__attribute__((address_space(3))) void*)la1, 16, 0, 0);
        __builtin_amdgcn_global_load_lds((const __attribute__((address_space(1))) void*)(gb0 + kt),
                                         (__attribute__((address_space(3))) void*)lb0, 16, 0, 0);
        __builtin_amdgcn_global_load_lds((const __attribute__((address_space(1))) void*)(gb1 + kt),
                                         (__attribute__((address_space(3))) void*)lb1, 16, 0, 0);
        __syncthreads();   // compiler emits vmcnt(0) drain -> LDS tiles valid
        bf16x8 af[4], bfr[4];
#pragma unroll
        for (int m = 0; m < 4; ++m)
            af[m] = *(const bf16x8*)&Als[(wr * 64 + m * 16) * 32 + fa];
#pragma unroll
        for (int n = 0; n < 4; ++n)
            bfr[n] = *(const bf16x8*)&Bls[(wc * 64 + n * 16) * 32 + fa];
#pragma unroll
        for (int m = 0; m < 4; ++m)
#pragma unroll
            for (int n = 0; n < 4; ++n)
                acc[m][n] = __builtin_amdgcn_mfma_f32_16x16x32_bf16(af[m], bfr[n], acc[m][n], 0, 0, 0);
        __syncthreads();
    }

#pragma unroll
    for (int m = 0; m < 4; ++m) {
#pragma unroll
        for (int n = 0; n < 4; ++n) {
#pragma unroll
            for (int j = 0; j < 4; ++j) {
                int row = brow + wr * 64 + m * 16 + (lane >> 4) * 4 + j;
                int col = bcol + wc * 64 + n * 16 + (lane & 15);
                size_t o = (size_t)row * N + col;
                float val = acc[m][n][j];
                if constexpr (EPI == 0) Cf[o] = val;
                else if constexpr (EPI == 2) Cf[o] = val + e0f[o];
                else if constexpr (EPI == 3) { float tt = fmaxf(val, 0.f); Cb[o] = f2bf(tt * tt); }
                else if constexpr (EPI == 5) Cb[o] = f2bf(1.f / (1.f + __expf(-val)));
                else if constexpr (EPI == 6) Cb[o] = f2bf(val);
                else if constexpr (EPI == 7) Cf[o] = Cf[o] + bf2f(e0b[o]) * val;
            }
        }
    }
}

extern "C" void kernel_launch(void* const* d_in, const int* in_sizes, int n_in,
                              void* d_out, int out_size, void* d_ws, size_t ws_size,
                              hipStream_t stream) {
    const float* x    = (const float*)d_in[0];
    const float* ln1w = (const float*)d_in[1];
    const float* ln1b = (const float*)d_in[2];
    const float* tmk  = (const float*)d_in[3];
    const float* tmv  = (const float*)d_in[4];
    const float* tmr  = (const float*)d_in[5];
    const float* Wk   = (const float*)d_in[6];
    const float* Wv   = (const float*)d_in[7];
    const float* Wr   = (const float*)d_in[8];
    const float* tf   = (const float*)d_in[9];
    const float* td   = (const float*)d_in[10];
    const float* Wo   = (const float*)d_in[11];
    const float* ln2w = (const float*)d_in[12];
    const float* ln2b = (const float*)d_in[13];
    const float* cmk  = (const float*)d_in[14];
    const float* cmr  = (const float*)d_in[15];
    const float* Wkf  = (const float*)d_in[16];
    const float* Wvf  = (const float*)d_in[17];
    const float* Wrf  = (const float*)d_in[18];
    float* out = (float*)d_out;

    char* ws = (char*)d_ws;
    size_t off = 0;
    auto alloc = [&](size_t bytes) {
        char* p = ws + off;
        off += (bytes + 255) & ~(size_t)255;
        return p;
    };
    // weights: 26 MB
    unsigned short* WkT  = (unsigned short*)alloc((size_t)C_ * C_ * 2);
    unsigned short* WvT  = (unsigned short*)alloc((size_t)C_ * C_ * 2);
    unsigned short* WrT  = (unsigned short*)alloc((size_t)C_ * C_ * 2);
    unsigned short* WoT  = (unsigned short*)alloc((size_t)C_ * C_ * 2);
    unsigned short* WrfT = (unsigned short*)alloc((size_t)C_ * C_ * 2);
    unsigned short* WkfT = (unsigned short*)alloc((size_t)C_ * FFN_ * 2);  // [FFN][C]
    unsigned short* WvfT = (unsigned short*)alloc((size_t)FFN_ * C_ * 2);  // [C][FFN]
    // three 32 MB bf16 [M][C] ping buffers (total ws ~128 MB)
    unsigned short* P1 = (unsigned short*)alloc((size_t)M_ * C_ * 2);  // kx -> v -> kx2
    unsigned short* P2 = (unsigned short*)alloc((size_t)M_ * C_ * 2);  // vx -> r -> rwkv(in-place) -> r2
    unsigned short* P3 = (unsigned short*)alloc((size_t)M_ * C_ * 2);  // rx -> rx2 -> vv chunks [M][1024]
    // k (f32) and att live in d_out (fully overwritten before each read stage)

    dim3 tb(32, 8);
    wconv_t<<<dim3(C_ / 32, C_ / 32), tb, 0, stream>>>(Wk, WkT, C_, C_);
    wconv_t<<<dim3(C_ / 32, C_ / 32), tb, 0, stream>>>(Wv, WvT, C_, C_);
    wconv_t<<<dim3(C_ / 32, C_ / 32), tb, 0, stream>>>(Wr, WrT, C_, C_);
    wconv_t<<<dim3(C_ / 32, C_ / 32), tb, 0, stream>>>(Wo, WoT, C_, C_);
    wconv_t<<<dim3(C_ / 32, C_ / 32), tb, 0, stream>>>(Wrf, WrfT, C_, C_);
    wconv_t<<<dim3(FFN_ / 32, C_ / 32), tb, 0, stream>>>(Wkf, WkfT, C_, FFN_);
    wconv_t<<<dim3(C_ / 32, FFN_ / 32), tb, 0, stream>>>(Wvf, WvfT, FFN_, C_);

    mix1_kernel<<<M_, 256, 0, stream>>>(x, ln1w, ln1b, tmk, tmv, tmr, P1, P2, P3);

    dim3 gC(C_ / 128, M_ / 128);
    gemm_bt<0><<<gC, 256, 0, stream>>>(P1, WkT, out, nullptr, nullptr, nullptr, M_, C_, C_, C_);      // k f32 -> out
    gemm_bt<6><<<gC, 256, 0, stream>>>(P2, WvT, nullptr, P1, nullptr, nullptr, M_, C_, C_, C_);       // v bf16 -> P1
    gemm_bt<5><<<gC, 256, 0, stream>>>(P3, WrT, nullptr, P2, nullptr, nullptr, M_, C_, C_, C_);       // r bf16 -> P2

    wkv_scan_kernel<<<(B_ * C_) / 64, 64, 0, stream>>>(out, P1, P2, tf, td);                          // rwkv in-place P2

    gemm_bt<2><<<gC, 256, 0, stream>>>(P2, WoT, out, nullptr, x, nullptr, M_, C_, C_, C_);            // att -> out

    mix2_kernel<<<M_, 256, 0, stream>>>(out, ln2w, ln2b, cmk, cmr, P1, P3);                           // kx2->P1, rx2->P3

    gemm_bt<5><<<gC, 256, 0, stream>>>(P3, WrfT, nullptr, P2, nullptr, nullptr, M_, C_, C_, C_);      // r2 bf16 -> P2

    for (int h = 0; h < 4; ++h) {
        gemm_bt<3><<<dim3(1024 / 128, M_ / 128), 256, 0, stream>>>(
            P1, WkfT + (size_t)h * 1024 * C_, nullptr, P3, nullptr, nullptr, M_, 1024, C_, C_);       // vv_h -> P3
        gemm_bt<7><<<gC, 256, 0, stream>>>(
            P3, WvfT + (size_t)h * 1024, out, nullptr, nullptr, P2, M_, C_, 1024, FFN_);              // out += r2*vv_h@Wvf_h
    }

    (void)in_sizes; (void)n_in; (void)out_size; (void)ws_size;
}

// Round 11
// 1259.298 us; speedup vs baseline: 1.1683x; 1.1683x over previous
//
#include <hip/hip_runtime.h>
#include <hip/hip_bf16.h>

#define B_   8
#define T_   2048
#define C_   1024
#define FFN_ 4096
#define M_   (B_ * T_)   // 16384
#define EPS_ 1e-5f
#define NC_  16          // scan chunks per sequence
#define LC_  (T_ / NC_)  // 128 steps per chunk

typedef __bf16 bf16x8 __attribute__((ext_vector_type(8)));
typedef float  f32x4  __attribute__((ext_vector_type(4)));

__device__ __forceinline__ unsigned short f2bf(float f) {
    union { float f; unsigned int u; } c; c.f = f;
    unsigned int u = c.u;
    u += 0x7fffu + ((u >> 16) & 1u);   // round-to-nearest-even
    return (unsigned short)(u >> 16);
}
__device__ __forceinline__ float bf2f(unsigned short h) {
    union { unsigned int u; float f; } c; c.u = ((unsigned int)h) << 16;
    return c.f;
}

// ---------------- weight fp32 [R][Cc] -> bf16 transposed [Cc][R] ----------------
__global__ __launch_bounds__(256) void wconv_t(const float* __restrict__ src,
                                               unsigned short* __restrict__ dst,
                                               int R, int Cc) {
    __shared__ float tile[32][33];
    int tx = threadIdx.x, ty = threadIdx.y;       // block (32,8)
    int c0 = blockIdx.x * 32;
    int r0 = blockIdx.y * 32;
#pragma unroll
    for (int i = 0; i < 4; ++i)
        tile[ty + i * 8][tx] = src[(size_t)(r0 + ty + i * 8) * Cc + c0 + tx];
    __syncthreads();
#pragma unroll
    for (int i = 0; i < 4; ++i)
        dst[(size_t)(c0 + ty + i * 8) * R + r0 + tx] = f2bf(tile[tx][ty + i * 8]);
}

// ---------------- block LN stats (256 threads, C=1024, float4/thread) ----------------
__device__ __forceinline__ void block_stats(const float4* __restrict__ p4, int tid,
                                            float* red, float& mean, float& rstd) {
    float4 v = p4[tid];
    float s = v.x + v.y + v.z + v.w;
    float q = v.x * v.x + v.y * v.y + v.z * v.z + v.w * v.w;
#pragma unroll
    for (int off = 32; off >= 1; off >>= 1) {
        s += __shfl_down(s, off, 64);
        q += __shfl_down(q, off, 64);
    }
    int lane = tid & 63, wv = tid >> 6;
    if (lane == 0) { red[wv] = s; red[4 + wv] = q; }
    __syncthreads();
    s = red[0] + red[1] + red[2] + red[3];
    q = red[4] + red[5] + red[6] + red[7];
    mean = s * (1.0f / C_);
    float var = q * (1.0f / C_) - mean * mean;
    rstd = rsqrtf(var + EPS_);
    __syncthreads();   // before red reuse
}

// ---------------- LN1 + token-shift + 3-way mix -> bf16 kx,vx,rx ----------------
__global__ __launch_bounds__(256) void mix1_kernel(
    const float* __restrict__ x, const float* __restrict__ lnw, const float* __restrict__ lnb,
    const float* __restrict__ tmk, const float* __restrict__ tmv, const float* __restrict__ tmr,
    unsigned short* __restrict__ kx, unsigned short* __restrict__ vx, unsigned short* __restrict__ rx) {
    __shared__ float red[8];
    int token = blockIdx.x;
    int t = token & (T_ - 1);
    int tid = threadIdx.x;
    bool hp = (t != 0);
    const float4* xt = (const float4*)(x + (size_t)token * C_);
    const float4* xp = (const float4*)(x + (size_t)(hp ? token - 1 : token) * C_);
    float m1, r1, m0 = 0.f, r0 = 0.f;
    block_stats(xt, tid, red, m1, r1);
    if (hp) block_stats(xp, tid, red, m0, r0);

    float4 xv = xt[tid];
    float4 pv = xp[tid];
    float4 w4 = ((const float4*)lnw)[tid];
    float4 b4 = ((const float4*)lnb)[tid];
    float4 k4 = ((const float4*)tmk)[tid];
    float4 v4 = ((const float4*)tmv)[tid];
    float4 q4 = ((const float4*)tmr)[tid];

    ushort4 ko, vo, ro;
    auto mixone = [&](float xe, float pe, float we, float be, float ke, float ve, float re,
                      unsigned short& koe, unsigned short& voe, unsigned short& roe) {
        float xn = (xe - m1) * r1 * we + be;
        float xs = hp ? ((pe - m0) * r0 * we + be) : 0.f;
        koe = f2bf(xs + ke * (xn - xs));
        voe = f2bf(xs + ve * (xn - xs));
        roe = f2bf(xs + re * (xn - xs));
    };
    mixone(xv.x, pv.x, w4.x, b4.x, k4.x, v4.x, q4.x, ko.x, vo.x, ro.x);
    mixone(xv.y, pv.y, w4.y, b4.y, k4.y, v4.y, q4.y, ko.y, vo.y, ro.y);
    mixone(xv.z, pv.z, w4.z, b4.z, k4.z, v4.z, q4.z, ko.z, vo.z, ro.z);
    mixone(xv.w, pv.w, w4.w, b4.w, k4.w, v4.w, q4.w, ko.w, vo.w, ro.w);
    size_t o = (size_t)token * (C_ / 4) + tid;
    ((ushort4*)kx)[o] = ko;
    ((ushort4*)vx)[o] = vo;
    ((ushort4*)rx)[o] = ro;
}

// ---------------- LN2 + token-shift + 2-way mix -> bf16 kx2,rx2 ----------------
__global__ __launch_bounds__(256) void mix2_kernel(
    const float* __restrict__ att, const float* __restrict__ lnw, const float* __restrict__ lnb,
    const float* __restrict__ cmk, const float* __restrict__ cmr,
    unsigned short* __restrict__ kx, unsigned short* __restrict__ rx) {
    __shared__ float red[8];
    int token = blockIdx.x;
    int t = token & (T_ - 1);
    int tid = threadIdx.x;
    bool hp = (t != 0);
    const float4* xt = (const float4*)(att + (size_t)token * C_);
    const float4* xp = (const float4*)(att + (size_t)(hp ? token - 1 : token) * C_);
    float m1, r1, m0 = 0.f, r0 = 0.f;
    block_stats(xt, tid, red, m1, r1);
    if (hp) block_stats(xp, tid, red, m0, r0);

    float4 xv = xt[tid];
    float4 pv = xp[tid];
    float4 w4 = ((const float4*)lnw)[tid];
    float4 b4 = ((const float4*)lnb)[tid];
    float4 k4 = ((const float4*)cmk)[tid];
    float4 q4 = ((const float4*)cmr)[tid];

    ushort4 ko, ro;
    auto mixone = [&](float xe, float pe, float we, float be, float ke, float re,
                      unsigned short& koe, unsigned short& roe) {
        float xn = (xe - m1) * r1 * we + be;
        float xs = hp ? ((pe - m0) * r0 * we + be) : 0.f;
        koe = f2bf(xs + ke * (xn - xs));
        roe = f2bf(xs + re * (xn - xs));
    };
    mixone(xv.x, pv.x, w4.x, b4.x, k4.x, q4.x, ko.x, ro.x);
    mixone(xv.y, pv.y, w4.y, b4.y, k4.y, q4.y, ko.y, ro.y);
    mixone(xv.z, pv.z, w4.z, b4.z, k4.z, q4.z, ko.z, ro.z);
    mixone(xv.w, pv.w, w4.w, b4.w, k4.w, q4.w, ko.w, ro.w);
    size_t o = (size_t)token * (C_ / 4) + tid;
    ((ushort4*)kx)[o] = ko;
    ((ushort4*)rx)[o] = ro;
}

// ---------------- WKV chunked scan (3 kernels) ----------------
// State (a,b,p) is log-scaled: actual sums are (a*e^p, b*e^p).
// A chunk of L steps maps incoming state by constant decay e^{w*L} plus its local summary.

// pass1: per (b,c,chunk<NC-1) local summary from zero state. Reads k (f32), v (bf16).
__global__ __launch_bounds__(256) void wkv_pass1(
    const float* __restrict__ k, const unsigned short* __restrict__ v,
    const float* __restrict__ td,
    float* __restrict__ SA, float* __restrict__ SB, float* __restrict__ SP) {
    int idx = blockIdx.x * 256 + threadIdx.x;   // 0 .. B*C*(NC-1)-1
    int c = idx & (C_ - 1);
    int b = (idx >> 10) & (B_ - 1);
    int ch = idx >> 13;
    float w = -expf(td[c]);
    size_t base = ((size_t)b * T_ + (size_t)ch * LC_) * C_ + c;
    float a = 0.f, bb = 0.f, p = -1e30f;

    float kA[8], vA[8], kB[8], vB[8];
#pragma unroll
    for (int j = 0; j < 8; ++j) {
        size_t o = base + (size_t)j * C_;
        kA[j] = k[o]; vA[j] = bf2f(v[o]);
    }
    auto step = [&](float kt, float vt) {
        float cw = w + p;
        float q2 = fmaxf(cw, kt);
        float f1 = __expf(cw - q2), f2e = __expf(kt - q2);
        a = f1 * a + f2e * vt;
        bb = f1 * bb + f2e;
        p = q2;
    };
    for (int t0 = 0; t0 < LC_; t0 += 16) {
#pragma unroll
        for (int j = 0; j < 8; ++j) {                 // t0+8..t0+15, always in-chunk
            size_t o = base + (size_t)(t0 + 8 + j) * C_;
            kB[j] = k[o]; vB[j] = bf2f(v[o]);
        }
#pragma unroll
        for (int j = 0; j < 8; ++j) step(kA[j], vA[j]);
#pragma unroll
        for (int j = 0; j < 8; ++j) {                 // t0+16..t0+23, clamp in-chunk
            int tt = t0 + 16 + j; if (tt > LC_ - 1) tt = LC_ - 1;
            size_t o = base + (size_t)tt * C_;
            kA[j] = k[o]; vA[j] = bf2f(v[o]);
        }
#pragma unroll
        for (int j = 0; j < 8; ++j) step(kB[j], vB[j]);
    }
    SA[idx] = a; SB[idx] = bb; SP[idx] = p;
}

// combine: per (b,c), sequential log-space prefix over NC summaries -> per-chunk entry states.
__global__ __launch_bounds__(256) void wkv_combine(
    const float* __restrict__ td,
    const float* __restrict__ SA, const float* __restrict__ SB, const float* __restrict__ SP,
    float* __restrict__ PA, float* __restrict__ PB, float* __restrict__ PP) {
    int idx = blockIdx.x * 256 + threadIdx.x;   // 0..B*C-1
    int c = idx & (C_ - 1);
    float wL = -expf(td[c]) * (float)LC_;
    float aP = 0.f, bP = 0.f, pP = -1e30f;
    PA[idx] = aP; PB[idx] = bP; PP[idx] = pP;   // chunk 0 entry
    for (int j = 1; j < NC_; ++j) {
        int s = (j - 1) * (B_ * C_) + idx;
        float as = SA[s], bs = SB[s], ps = SP[s];
        float pd = pP + wL;
        float q = fmaxf(pd, ps);
        float e1 = __expf(pd - q), e2 = __expf(ps - q);
        aP = e1 * aP + e2 * as;
        bP = e1 * bP + e2 * bs;
        pP = q;
        int d = j * (B_ * C_) + idx;
        PA[d] = aP; PB[d] = bP; PP[d] = pP;
    }
}

// pass2: per (b,c,chunk) full scan from entry state; writes bf16(r*wkv) IN PLACE over r.
// Prefetch clamped in-chunk so no cross-thread read of the in-place buffer.
__global__ __launch_bounds__(256) void wkv_pass2(
    const float* __restrict__ k, const unsigned short* __restrict__ v,
    unsigned short* rv,
    const float* __restrict__ tf, const float* __restrict__ td,
    const float* __restrict__ PA, const float* __restrict__ PB, const float* __restrict__ PP) {
    int idx = blockIdx.x * 256 + threadIdx.x;   // 0..B*C*NC-1
    int c = idx & (C_ - 1);
    int b = (idx >> 10) & (B_ - 1);
    int ch = idx >> 13;
    float w = -expf(td[c]);
    float u = tf[c];
    size_t base = ((size_t)b * T_ + (size_t)ch * LC_) * C_ + c;
    float a = PA[idx], bb = PB[idx], p = PP[idx];

    float kA[8], vA[8], rA[8], kB[8], vB[8], rB[8];
#pragma unroll
    for (int j = 0; j < 8; ++j) {
        size_t o = base + (size_t)j * C_;
        kA[j] = k[o]; vA[j] = bf2f(v[o]); rA[j] = bf2f(rv[o]);
    }
    auto step = [&](float kt, float vt, float rt, int t) {
        float uk = u + kt;
        float qq = fmaxf(p, uk);
        float e1 = __expf(p - qq), e2 = __expf(uk - qq);
        float num = e1 * a + e2 * vt;
        float den = e1 * bb + e2;
        float wkv = (den == 0.f) ? 0.f : num / den;
        rv[base + (size_t)t * C_] = f2bf(rt * wkv);
        float cw = w + p;
        float q2 = fmaxf(cw, kt);
        float f1 = __expf(cw - q2), f2e = __expf(kt - q2);
        a = f1 * a + f2e * vt;
        bb = f1 * bb + f2e;
        p = q2;
    };
    for (int t0 = 0; t0 < LC_; t0 += 16) {
#pragma unroll
        for (int j = 0; j < 8; ++j) {                 // t0+8..t0+15, in-chunk
            size_t o = base + (size_t)(t0 + 8 + j) * C_;
            kB[j] = k[o]; vB[j] = bf2f(v[o]); rB[j] = bf2f(rv[o]);
        }
#pragma unroll
        for (int j = 0; j < 8; ++j) step(kA[j], vA[j], rA[j], t0 + j);
#pragma unroll
        for (int j = 0; j < 8; ++j) {                 // t0+16..t0+23, clamp in-chunk
            int tt = t0 + 16 + j; if (tt > LC_ - 1) tt = LC_ - 1;
            size_t o = base + (size_t)tt * C_;
            kA[j] = k[o]; vA[j] = bf2f(v[o]); rA[j] = bf2f(rv[o]);
        }
#pragma unroll
        for (int j = 0; j < 8; ++j) step(kB[j], vB[j], rB[j], t0 + 8 + j);
    }
}

// ---------------- bf16 GEMM: C[M,N] = A[M,K] @ Bt[N,K]^T, m97-style 128^2 tile ----------------
// A row stride = K; Bt row stride = ldb (>= K, for FFN-chunked B).
// EPI: 0 = store f32; 2 = +e0f f32; 3 = relu^2 -> bf16; 5 = sigmoid -> bf16;
//      6 = store bf16; 7 = Cf[o] += bf2f(e0b[o]) * val (in-place f32 accumulate)
template<int EPI>
__global__ __launch_bounds__(256) void gemm_bt(
    const unsigned short* __restrict__ A, const unsigned short* __restrict__ Bt,
    float* Cf, unsigned short* Cb,
    const float* __restrict__ e0f, const unsigned short* __restrict__ e0b,
    int M, int N, int K, int ldb) {
    __shared__ unsigned short Als[128 * 32];
    __shared__ unsigned short Bls[128 * 32];
    int tid = threadIdx.x;
    int lane = tid & 63, wv = tid >> 6;
    int wr = wv >> 1, wc = wv & 1;
    int brow = blockIdx.y * 128, bcol = blockIdx.x * 128;

    f32x4 acc[4][4] = {};

    int ar = tid >> 2, ac = (tid & 3) * 8;  // 16B chunk -> (row, col8) within tile
    const unsigned short* ga0 = A + (size_t)(brow + ar) * K + ac;
    const unsigned short* ga1 = A + (size_t)(brow + 64 + ar) * K + ac;
    const unsigned short* gb0 = Bt + (size_t)(bcol + ar) * ldb + ac;
    const unsigned short* gb1 = Bt + (size_t)(bcol + 64 + ar) * ldb + ac;
    unsigned short* la0 = Als + (size_t)(wv * 64) * 8;         // + lane*16B implicit
    unsigned short* la1 = Als + (size_t)((4 + wv) * 64) * 8;
    unsigned short* lb0 = Bls + (size_t)(wv * 64) * 8;
    unsigned short* lb1 = Bls + (size_t)((4 + wv) * 64) * 8;

    int fa = (lane & 15) * 32 + (lane >> 4) * 8;  // fragment base offset

    for (int kt = 0; kt < K; kt += 32) {
        __builtin_amdgcn_global_load_lds((const __attribute__((address_space(1))) void*)(ga0 + kt),
                                         (__attribute__((address_space(3))) void*)la0, 16, 0, 0);
        __builtin_amdgcn_global_load_lds((const __attribute__((address_space(1))) void*)(ga1 + kt),
                                         (__attribute__((address_space(3))) void*)la1, 16, 0, 0);
        __builtin_amdgcn_global_load_lds((const __attribute__((address_space(1))) void*)(gb0 + kt),
                                         (__attribute__((address_space(3))) void*)lb0, 16, 0, 0);
        __builtin_amdgcn_global_load_lds((const __attribute__((address_space(1))) void*)(gb1 + kt),
                                         (__attribute__((address_space(3))) void*)lb1, 16, 0, 0);
        __syncthreads();   // compiler emits vmcnt(0) drain -> LDS tiles valid
        bf16x8 af[4], bfr[4];
#pragma unroll
        for (int m = 0; m < 4; ++m)
            af[m] = *(const bf16x8*)&Als[(wr * 64 + m * 16) * 32 + fa];
#pragma unroll
        for (int n = 0; n < 4; ++n)
            bfr[n] = *(const bf16x8*)&Bls[(wc * 64 + n * 16) * 32 + fa];
#pragma unroll
        for (int m = 0; m < 4; ++m)
#pragma unroll
            for (int n = 0; n < 4; ++n)
                acc[m][n] = __builtin_amdgcn_mfma_f32_16x16x32_bf16(af[m], bfr[n], acc[m][n], 0, 0, 0);
        __syncthreads();
    }

#pragma unroll
    for (int m = 0; m < 4; ++m) {
#pragma unroll
        for (int n = 0; n < 4; ++n) {
#pragma unroll
            for (int j = 0; j < 4; ++j) {
                int row = brow + wr * 64 + m * 16 + (lane >> 4) * 4 + j;
                int col = bcol + wc * 64 + n * 16 + (lane & 15);
                size_t o = (size_t)row * N + col;
                float val = acc[m][n][j];
                if constexpr (EPI == 0) Cf[o] = val;
                else if constexpr (EPI == 2) Cf[o] = val + e0f[o];
                else if constexpr (EPI == 3) { float tt = fmaxf(val, 0.f); Cb[o] = f2bf(tt * tt); }
                else if constexpr (EPI == 5) Cb[o] = f2bf(1.f / (1.f + __expf(-val)));
                else if constexpr (EPI == 6) Cb[o] = f2bf(val);
                else if constexpr (EPI == 7) Cf[o] = Cf[o] + bf2f(e0b[o]) * val;
            }
        }
    }
}

extern "C" void kernel_launch(void* const* d_in, const int* in_sizes, int n_in,
                              void* d_out, int out_size, void* d_ws, size_t ws_size,
                              hipStream_t stream) {
    const float* x    = (const float*)d_in[0];
    const float* ln1w = (const float*)d_in[1];
    const float* ln1b = (const float*)d_in[2];
    const float* tmk  = (const float*)d_in[3];
    const float* tmv  = (const float*)d_in[4];
    const float* tmr  = (const float*)d_in[5];
    const float* Wk   = (const float*)d_in[6];
    const float* Wv   = (const float*)d_in[7];
    const float* Wr   = (const float*)d_in[8];
    const float* tf   = (const float*)d_in[9];
    const float* td   = (const float*)d_in[10];
    const float* Wo   = (const float*)d_in[11];
    const float* ln2w = (const float*)d_in[12];
    const float* ln2b = (const float*)d_in[13];
    const float* cmk  = (const float*)d_in[14];
    const float* cmr  = (const float*)d_in[15];
    const float* Wkf  = (const float*)d_in[16];
    const float* Wvf  = (const float*)d_in[17];
    const float* Wrf  = (const float*)d_in[18];
    float* out = (float*)d_out;

    char* ws = (char*)d_ws;
    size_t off = 0;
    auto alloc = [&](size_t bytes) {
        char* p = ws + off;
        off += (bytes + 255) & ~(size_t)255;
        return p;
    };
    // weights: 26 MB
    unsigned short* WkT  = (unsigned short*)alloc((size_t)C_ * C_ * 2);
    unsigned short* WvT  = (unsigned short*)alloc((size_t)C_ * C_ * 2);
    unsigned short* WrT  = (unsigned short*)alloc((size_t)C_ * C_ * 2);
    unsigned short* WoT  = (unsigned short*)alloc((size_t)C_ * C_ * 2);
    unsigned short* WrfT = (unsigned short*)alloc((size_t)C_ * C_ * 2);
    unsigned short* WkfT = (unsigned short*)alloc((size_t)C_ * FFN_ * 2);  // [FFN][C]
    unsigned short* WvfT = (unsigned short*)alloc((size_t)FFN_ * C_ * 2);  // [C][FFN]
    // three 32 MB bf16 [M][C] ping buffers
    unsigned short* P1 = (unsigned short*)alloc((size_t)M_ * C_ * 2);  // kx -> v -> kx2
    unsigned short* P2 = (unsigned short*)alloc((size_t)M_ * C_ * 2);  // vx -> r -> rwkv(in-place) -> r2
    unsigned short* P3 = (unsigned short*)alloc((size_t)M_ * C_ * 2);  // rx -> rx2 -> vv chunks [M][1024]
    // scan chunk summaries / prefixes: 6 x 512 KB
    float* SA = (float*)alloc((size_t)NC_ * B_ * C_ * 4);
    float* SB = (float*)alloc((size_t)NC_ * B_ * C_ * 4);
    float* SP = (float*)alloc((size_t)NC_ * B_ * C_ * 4);
    float* PA = (float*)alloc((size_t)NC_ * B_ * C_ * 4);
    float* PBp = (float*)alloc((size_t)NC_ * B_ * C_ * 4);
    float* PP = (float*)alloc((size_t)NC_ * B_ * C_ * 4);
    // k (f32) and att live in d_out (fully overwritten before each read stage)

    dim3 tb(32, 8);
    wconv_t<<<dim3(C_ / 32, C_ / 32), tb, 0, stream>>>(Wk, WkT, C_, C_);
    wconv_t<<<dim3(C_ / 32, C_ / 32), tb, 0, stream>>>(Wv, WvT, C_, C_);
    wconv_t<<<dim3(C_ / 32, C_ / 32), tb, 0, stream>>>(Wr, WrT, C_, C_);
    wconv_t<<<dim3(C_ / 32, C_ / 32), tb, 0, stream>>>(Wo, WoT, C_, C_);
    wconv_t<<<dim3(C_ / 32, C_ / 32), tb, 0, stream>>>(Wrf, WrfT, C_, C_);
    wconv_t<<<dim3(FFN_ / 32, C_ / 32), tb, 0, stream>>>(Wkf, WkfT, C_, FFN_);
    wconv_t<<<dim3(C_ / 32, FFN_ / 32), tb, 0, stream>>>(Wvf, WvfT, FFN_, C_);

    mix1_kernel<<<M_, 256, 0, stream>>>(x, ln1w, ln1b, tmk, tmv, tmr, P1, P2, P3);

    dim3 gC(C_ / 128, M_ / 128);
    gemm_bt<0><<<gC, 256, 0, stream>>>(P1, WkT, out, nullptr, nullptr, nullptr, M_, C_, C_, C_);      // k f32 -> out
    gemm_bt<6><<<gC, 256, 0, stream>>>(P2, WvT, nullptr, P1, nullptr, nullptr, M_, C_, C_, C_);       // v bf16 -> P1
    gemm_bt<5><<<gC, 256, 0, stream>>>(P3, WrT, nullptr, P2, nullptr, nullptr, M_, C_, C_, C_);       // r bf16 -> P2

    wkv_pass1<<<(B_ * C_ * (NC_ - 1)) / 256, 256, 0, stream>>>(out, P1, td, SA, SB, SP);
    wkv_combine<<<(B_ * C_) / 256, 256, 0, stream>>>(td, SA, SB, SP, PA, PBp, PP);
    wkv_pass2<<<(B_ * C_ * NC_) / 256, 256, 0, stream>>>(out, P1, P2, tf, td, PA, PBp, PP);           // rwkv in-place P2

    gemm_bt<2><<<gC, 256, 0, stream>>>(P2, WoT, out, nullptr, x, nullptr, M_, C_, C_, C_);            // att -> out

    mix2_kernel<<<M_, 256, 0, stream>>>(out, ln2w, ln2b, cmk, cmr, P1, P3);                           // kx2->P1, rx2->P3

    gemm_bt<5><<<gC, 256, 0, stream>>>(P3, WrfT, nullptr, P2, nullptr, nullptr, M_, C_, C_, C_);      // r2 bf16 -> P2

    for (int h = 0; h < 4; ++h) {
        gemm_bt<3><<<dim3(1024 / 128, M_ / 128), 256, 0, stream>>>(
            P1, WkfT + (size_t)h * 1024 * C_, nullptr, P3, nullptr, nullptr, M_, 1024, C_, C_);       // vv_h -> P3
        gemm_bt<7><<<gC, 256, 0, stream>>>(
            P3, WvfT + (size_t)h * 1024, out, nullptr, nullptr, P2, M_, C_, 1024, FFN_);              // out += r2*vv_h@Wvf_h
    }

    (void)in_sizes; (void)n_in; (void)out_size; (void)ws_size;
}